// Round 8
// baseline (36.103 us; speedup 1.0000x reference)
//
#include <hip/hip_runtime.h>
#include <math.h>

namespace {
constexpr int R_RUNS   = 4096;
constexpr int T_STEPS  = 2048;
constexpr int K_CHUNKS = 64;                 // chunks per run (KB tiling)
constexpr int L_CHUNK  = 32;                 // timesteps per chunk (KB tiling)
constexpr int NG       = 64;                 // run groups (64 runs each)
constexpr int PAD_T    = 33;                 // tile row stride (conflict-free)
constexpr int QSTRIDE  = 32;                 // Q row stride in floats (128B)
}

__device__ __forceinline__ float sigmoidf_(float x) {
    return 1.0f / (1.0f + expf(-x));
}

__device__ __forceinline__ float dot8u(const float* __restrict__ p, const float m[8]) {
    float s = p[0] * m[0];
    s = fmaf(p[1], m[1], s);
    s = fmaf(p[2], m[2], s);
    s = fmaf(p[3], m[3], s);
    s = fmaf(p[4], m[4], s);
    s = fmaf(p[5], m[5], s);
    s = fmaf(p[6], m[6], s);
    s = fmaf(p[7], m[7], s);
    return s;
}

// ---------------------------------------------------------------------------
// K1: block 0 builds Q[t] = [x_t | z_t | W_t | pad], W_t = gh*W_{t-1} + z_{t-1},
//     W_0 = 0, gh = sigmoid(G[0])  (2-level scan: 8 comps x 32 chunks of 64 t).
//     All other blocks: per-wave uniformity check; only if a wave's G values
//     differ from G[0] does it compute the U chunk summaries (exact fallback).
// ---------------------------------------------------------------------------
extern "C" __global__ __launch_bounds__(256, 4)
void dlm_k1_prepare(const float* __restrict__ Xt, const float* __restrict__ Zt,
                    const float* __restrict__ G, const float* __restrict__ gamma,
                    float* __restrict__ U, float* __restrict__ Q)
{
    __shared__ float sumLDS[32 * 8];

    const int tid  = threadIdx.x;
    const int wid  = __builtin_amdgcn_readfirstlane((int)(tid >> 6));
    const int lane = tid & 63;
    const int wave = blockIdx.x * 4 + wid;
    const int g    = wave & (NG - 1);
    const int k    = wave >> 6;
    const int r    = (g << 6) + lane;

    const float G0 = G[0];
    const float gr = G[r];
    const bool uni = (__ballot(gr == G0) == ~0ull);

    if (!uni) {
        // exact fallback: chunk summaries U[k][r] (R7 path)
        const float4 g0 = *reinterpret_cast<const float4*>(gamma + (size_t)r * 8);
        const float4 g1 = *reinterpret_cast<const float4*>(gamma + (size_t)r * 8 + 4);
        const float gm[8] = {g0.x, g0.y, g0.z, g0.w, g1.x, g1.y, g1.z, g1.w};
        const float gh = sigmoidf_(gr);
        const int t0 = k * L_CHUNK;
        const float* __restrict__ zbase = Zt + (size_t)t0 * 8;
        float b_prev = (k > 0) ? dot8u(zbase - 8, gm) : 0.0f;
        float u = 0.0f;
        #pragma unroll
        for (int j = 0; j < L_CHUNK; ++j) {
            u = fmaf(gh, u, b_prev);
            b_prev = dot8u(zbase + j * 8, gm);
        }
        U[(size_t)k * R_RUNS + r] = u;
    }

    if (blockIdx.x != 0) return;

    // ================= block 0: assemble Q =================
    const float gh = sigmoidf_(G0);

    // ---- copy x,z into Q rows (coalesced float4 reads)
    #pragma unroll
    for (int v = tid; v < 4096; v += 256) {
        const int t = v >> 1, h = v & 1;
        const float4 xa = reinterpret_cast<const float4*>(Xt)[v];
        *reinterpret_cast<float4*>(Q + (size_t)t * QSTRIDE + h * 4) = xa;
        const float4 za = reinterpret_cast<const float4*>(Zt)[v];
        *reinterpret_cast<float4*>(Q + (size_t)t * QSTRIDE + 8 + h * 4) = za;
    }

    // ---- W scan: thread (c = tid&7, j = tid>>3), chunk j covers t in [64j, 64j+64)
    const int c = tid & 7;
    const int j = tid >> 3;

    // phase A: S_j = sum_{m=0..63} gh^{63-m} z[64j+m][c]
    float s = 0.0f;
    #pragma unroll 4
    for (int m = 0; m < 64; ++m)
        s = fmaf(gh, s, Zt[(size_t)(64 * j + m) * 8 + c]);
    sumLDS[j * 8 + c] = s;
    __syncthreads();

    // phase B: Wstart(j) = W_{64j} = sum_{i<j} (gh^64)^{j-1-i} S_i
    float gh64 = gh;
    #pragma unroll
    for (int i = 0; i < 6; ++i) gh64 = gh64 * gh64;
    float w = 0.0f;
    for (int i = 0; i < j; ++i)
        w = fmaf(gh64, w, sumLDS[i * 8 + c]);

    // phase C: replay & emit W_t
    float Wt = w;
    #pragma unroll 4
    for (int i = 0; i < 64; ++i) {
        const int t = 64 * j + i;
        Q[(size_t)t * QSTRIDE + 16 + c] = Wt;
        Wt = fmaf(gh, Wt, Zt[(size_t)t * 8 + c]);   // W_{t+1} = gh*W_t + z_t
    }
}

// ---------------------------------------------------------------------------
// KB: out[r][t] = [eta_r|zeta_r|gamma_r] . Q[t]  (rank-24 dot, Q wave-uniform
// -> s_load rows; zero serial dependencies). Exact R7 recurrence fallback if
// the wave's G values are not all == G[0]. LDS tile + coalesced flush.
// ---------------------------------------------------------------------------
extern "C" __global__ __launch_bounds__(256, 4)
void dlm_kb_output(const float* __restrict__ Xt, const float* __restrict__ Zt,
                   const float* __restrict__ G, const float* __restrict__ eta,
                   const float* __restrict__ zeta, const float* __restrict__ gamma,
                   const float* __restrict__ U, const float* __restrict__ Q,
                   float* __restrict__ out)
{
    __shared__ float tile[4][64][PAD_T];

    const int tid  = threadIdx.x;
    const int wid  = __builtin_amdgcn_readfirstlane((int)(tid >> 6));
    const int lane = tid & 63;
    const int wave = blockIdx.x * 4 + wid;
    const int g    = wave & (NG - 1);
    const int k    = wave >> 6;
    const int r    = (g << 6) + lane;
    const int t0   = k * L_CHUNK;

    const float4 g0 = *reinterpret_cast<const float4*>(gamma + (size_t)r * 8);
    const float4 g1 = *reinterpret_cast<const float4*>(gamma + (size_t)r * 8 + 4);
    const float4 e0 = *reinterpret_cast<const float4*>(eta   + (size_t)r * 8);
    const float4 e1 = *reinterpret_cast<const float4*>(eta   + (size_t)r * 8 + 4);
    const float4 z0 = *reinterpret_cast<const float4*>(zeta  + (size_t)r * 8);
    const float4 z1 = *reinterpret_cast<const float4*>(zeta  + (size_t)r * 8 + 4);
    const float gm[8] = {g0.x, g0.y, g0.z, g0.w, g1.x, g1.y, g1.z, g1.w};
    const float et[8] = {e0.x, e0.y, e0.z, e0.w, e1.x, e1.y, e1.z, e1.w};
    const float zz[8] = {z0.x, z0.y, z0.z, z0.w, z1.x, z1.y, z1.z, z1.w};

    const float G0 = G[0];
    const float gr = G[r];
    const bool uni = (__ballot(gr == G0) == ~0ull);

    if (uni) {
        // ---- rank-24 GEMM path: no recurrence, no scan
        #pragma unroll
        for (int j = 0; j < L_CHUNK; ++j) {
            const float* __restrict__ q = Q + (size_t)(t0 + j) * QSTRIDE;  // uniform
            float s = q[0] * et[0];
            #pragma unroll
            for (int i = 1; i < 8; ++i) s = fmaf(q[i], et[i], s);
            #pragma unroll
            for (int i = 0; i < 8; ++i) s = fmaf(q[8 + i], zz[i], s);
            #pragma unroll
            for (int i = 0; i < 8; ++i) s = fmaf(q[16 + i], gm[i], s);
            tile[wid][lane][j] = s;
        }
    } else {
        // ---- exact fallback: R7 recurrence path
        const float gh = sigmoidf_(gr);
        float A = gh;
        #pragma unroll
        for (int i = 0; i < 5; ++i) A = A * A;   // gh^32

        float theta = 0.0f;
        #pragma unroll
        for (int base = 0; base < K_CHUNKS; base += 8) {
            if (base < k) {
                float v[8];
                #pragma unroll
                for (int i = 0; i < 8; ++i)
                    v[i] = U[(size_t)(base + i) * R_RUNS + r];
                #pragma unroll
                for (int i = 0; i < 8; ++i) {
                    const bool act = (base + i) < k;
                    theta = fmaf(act ? A : 1.0f, theta, act ? v[i] : 0.0f);
                }
            }
        }

        const float* __restrict__ zbase = Zt + (size_t)t0 * 8;
        const float* __restrict__ xbase = Xt + (size_t)t0 * 8;
        float b_prev = (k > 0) ? dot8u(zbase - 8, gm) : 0.0f;
        #pragma unroll
        for (int j = 0; j < L_CHUNK; ++j) {
            const float* __restrict__ zr = zbase + j * 8;
            const float* __restrict__ xr = xbase + j * 8;
            float bx = xr[0] * et[0], bz = zr[0] * zz[0], bn = zr[0] * gm[0];
            #pragma unroll
            for (int q2 = 1; q2 < 8; ++q2) {
                bx = fmaf(xr[q2], et[q2], bx);
                bz = fmaf(zr[q2], zz[q2], bz);
                bn = fmaf(zr[q2], gm[q2], bn);
            }
            theta = fmaf(gh, theta, b_prev);
            b_prev = bn;
            tile[wid][lane][j] = theta + bx + bz;
        }
    }

    // ---- flush (wave-private tile): 2 rows x 128B contiguous per instr
    const int rrh = lane >> 5;
    const int c   = lane & 31;
    #pragma unroll
    for (int it = 0; it < 32; ++it) {
        const int rr = it * 2 + rrh;
        out[(size_t)((g << 6) + rr) * T_STEPS + t0 + c] = tile[wid][rr][c];
    }
}

// ---------------------------------------------------------------------------
extern "C" void kernel_launch(void* const* d_in, const int* in_sizes, int n_in,
                              void* d_out, int out_size, void* d_ws, size_t ws_size,
                              hipStream_t stream)
{
    const float* Xt    = (const float*)d_in[0];
    const float* Zt    = (const float*)d_in[1];
    const float* G     = (const float*)d_in[2];
    const float* eta   = (const float*)d_in[3];
    const float* zeta  = (const float*)d_in[4];
    const float* gamma = (const float*)d_in[5];
    float* out = (float*)d_out;

    // ws: U[64][4096] (1 MB) | Q[2048][32] (256 KB)
    float* U = (float*)d_ws;
    float* Q = U + (size_t)K_CHUNKS * R_RUNS;

    const dim3 blk(256);
    const dim3 grid(NG * K_CHUNKS / 4);       // 1024 blocks (4 waves each)

    dlm_k1_prepare<<<grid, blk, 0, stream>>>(Xt, Zt, G, gamma, U, Q);
    dlm_kb_output <<<grid, blk, 0, stream>>>(Xt, Zt, G, eta, zeta, gamma, U, Q, out);
}

// Round 9
// 34.979 us; speedup vs baseline: 1.0321x; 1.0321x over previous
//
#include <hip/hip_runtime.h>
#include <math.h>

namespace {
constexpr int R_RUNS   = 4096;
constexpr int T_STEPS  = 2048;
constexpr int K_CHUNKS = 64;                 // U chunks per run (fallback)
constexpr int L_CHUNK  = 32;                 // timesteps per U chunk (fallback)
constexpr int NG       = 64;                 // run groups of 64 (K1 mapping)
constexpr int TBW      = 64;                 // t per wave (KB)
constexpr int RPW      = 32;                 // r per wave (KB)
}

__device__ __forceinline__ float sigmoidf_(float x) {
    return 1.0f / (1.0f + expf(-x));
}

__device__ __forceinline__ float dot8u(const float* __restrict__ p, const float m[8]) {
    float s = p[0] * m[0];
    s = fmaf(p[1], m[1], s);
    s = fmaf(p[2], m[2], s);
    s = fmaf(p[3], m[3], s);
    s = fmaf(p[4], m[4], s);
    s = fmaf(p[5], m[5], s);
    s = fmaf(p[6], m[6], s);
    s = fmaf(p[7], m[7], s);
    return s;
}

// ---------------------------------------------------------------------------
// K1: block 0 builds W[t][c] (t=0..2047, c=0..7), W_{t+1} = gh*W_t + z_t,
//     W_0 = 0, gh = sigmoid(G[0]); 2-level scan with 256 threads
//     (thread (c,j): chunk j of 64 steps). No Q assembly (KB reads X/Z direct).
//     All waves: uniformity check vs G[0]; non-uniform waves write exact U
//     chunk summaries (R7 path) for the fallback.
// ---------------------------------------------------------------------------
extern "C" __global__ __launch_bounds__(256, 4)
void dlm_k1(const float* __restrict__ Zt, const float* __restrict__ G,
            const float* __restrict__ gamma, float* __restrict__ U,
            float* __restrict__ W)
{
    __shared__ float sumLDS[32 * 8];

    const int tid  = threadIdx.x;
    const int wid  = __builtin_amdgcn_readfirstlane((int)(tid >> 6));
    const int lane = tid & 63;
    const int wave = blockIdx.x * 4 + wid;
    const int g    = wave & (NG - 1);
    const int k    = wave >> 6;
    const int r    = (g << 6) + lane;

    const float G0 = G[0];
    const float gr = G[r];
    const bool uni = (__ballot(gr == G0) == ~0ull);

    if (!uni) {
        // exact fallback: U[k][r] chunk summaries (proven R7 path)
        const float4 g0 = *reinterpret_cast<const float4*>(gamma + (size_t)r * 8);
        const float4 g1 = *reinterpret_cast<const float4*>(gamma + (size_t)r * 8 + 4);
        const float gm[8] = {g0.x, g0.y, g0.z, g0.w, g1.x, g1.y, g1.z, g1.w};
        const float gh = sigmoidf_(gr);
        const int t0 = k * L_CHUNK;
        const float* __restrict__ zbase = Zt + (size_t)t0 * 8;
        float b_prev = (k > 0) ? dot8u(zbase - 8, gm) : 0.0f;
        float u = 0.0f;
        #pragma unroll
        for (int j = 0; j < L_CHUNK; ++j) {
            u = fmaf(gh, u, b_prev);
            b_prev = dot8u(zbase + j * 8, gm);
        }
        U[(size_t)k * R_RUNS + r] = u;
    }

    if (blockIdx.x != 0) return;

    // ================= block 0: W scan =================
    const float gh = sigmoidf_(G0);
    const int c = tid & 7;
    const int j = tid >> 3;          // chunk of 64 timesteps

    // phase A: S_j = sum_{m=0..63} gh^{63-m} z[64j+m][c]
    float s = 0.0f;
    #pragma unroll 4
    for (int m = 0; m < 64; ++m)
        s = fmaf(gh, s, Zt[(size_t)(64 * j + m) * 8 + c]);
    sumLDS[j * 8 + c] = s;
    __syncthreads();

    // phase B: W_{64j} = sum_{i<j} (gh^64)^{j-1-i} S_i
    float gh64 = gh;
    #pragma unroll
    for (int i = 0; i < 6; ++i) gh64 = gh64 * gh64;
    float w = 0.0f;
    for (int i = 0; i < j; ++i)
        w = fmaf(gh64, w, sumLDS[i * 8 + c]);

    // phase C: emit W_t, advance W_{t+1} = gh*W_t + z_t
    float Wt = w;
    #pragma unroll 4
    for (int i = 0; i < 64; ++i) {
        const int t = 64 * j + i;
        W[(size_t)t * 8 + c] = Wt;
        Wt = fmaf(gh, Wt, Zt[(size_t)t * 8 + c]);
    }
}

// ---------------------------------------------------------------------------
// KB: lane = t. Wave covers 64 consecutive t x 32 r.
// Fast path: out[r][t] = eta_r.x_t + zeta_r.z_t + gamma_r.W_t
//   x/z/W per-lane coalesced VMEM float4s; params via wave-uniform s_load;
//   direct 256B-coalesced dword stores. No LDS, no scan, no recurrence.
// Fallback (any of the wave's 32 G's != G[0]): exact serial per-r replay
//   from U chunk summaries (slow, correctness-only).
// ---------------------------------------------------------------------------
extern "C" __global__ __launch_bounds__(256, 4)
void dlm_kb(const float* __restrict__ Xt, const float* __restrict__ Zt,
            const float* __restrict__ G, const float* __restrict__ eta,
            const float* __restrict__ zeta, const float* __restrict__ gamma,
            const float* __restrict__ U, const float* __restrict__ W,
            float* __restrict__ out)
{
    const int tid  = threadIdx.x;
    const int wid  = __builtin_amdgcn_readfirstlane((int)(tid >> 6));
    const int lane = tid & 63;
    const int wave = blockIdx.x * 4 + wid;
    const int tb   = wave & 31;          // t block (64 wide)
    const int rg   = wave >> 5;          // r group (32 runs)
    const int t0   = tb * TBW;
    const int r0   = rg * RPW;
    const int t    = t0 + lane;

    // per-lane operand vectors (coalesced, 32B stride)
    const float4 xa = *reinterpret_cast<const float4*>(Xt + (size_t)t * 8);
    const float4 xb = *reinterpret_cast<const float4*>(Xt + (size_t)t * 8 + 4);
    const float4 za = *reinterpret_cast<const float4*>(Zt + (size_t)t * 8);
    const float4 zb = *reinterpret_cast<const float4*>(Zt + (size_t)t * 8 + 4);
    const float4 wa = *reinterpret_cast<const float4*>(W  + (size_t)t * 8);
    const float4 wb = *reinterpret_cast<const float4*>(W  + (size_t)t * 8 + 4);

    const float G0 = G[0];
    const float gv = G[r0 + (lane & 31)];
    const bool uni = (__ballot(gv == G0) == ~0ull);

    if (uni) {
        #pragma unroll 4
        for (int rr = 0; rr < RPW; ++rr) {
            const float* __restrict__ e  = eta   + (size_t)(r0 + rr) * 8;  // uniform
            const float* __restrict__ zc = zeta  + (size_t)(r0 + rr) * 8;  // uniform
            const float* __restrict__ gc = gamma + (size_t)(r0 + rr) * 8;  // uniform
            float s = xa.x * e[0];
            s = fmaf(xa.y, e[1], s);
            s = fmaf(xa.z, e[2], s);
            s = fmaf(xa.w, e[3], s);
            s = fmaf(xb.x, e[4], s);
            s = fmaf(xb.y, e[5], s);
            s = fmaf(xb.z, e[6], s);
            s = fmaf(xb.w, e[7], s);
            s = fmaf(za.x, zc[0], s);
            s = fmaf(za.y, zc[1], s);
            s = fmaf(za.z, zc[2], s);
            s = fmaf(za.w, zc[3], s);
            s = fmaf(zb.x, zc[4], s);
            s = fmaf(zb.y, zc[5], s);
            s = fmaf(zb.z, zc[6], s);
            s = fmaf(zb.w, zc[7], s);
            s = fmaf(wa.x, gc[0], s);
            s = fmaf(wa.y, gc[1], s);
            s = fmaf(wa.z, gc[2], s);
            s = fmaf(wa.w, gc[3], s);
            s = fmaf(wb.x, gc[4], s);
            s = fmaf(wb.y, gc[5], s);
            s = fmaf(wb.z, gc[6], s);
            s = fmaf(wb.w, gc[7], s);
            out[(size_t)(r0 + rr) * T_STEPS + t] = s;
        }
    } else {
        // exact, slow fallback: serial replay per r from U summaries
        for (int rr = 0; rr < RPW; ++rr) {
            const int r = r0 + rr;
            const float* __restrict__ gc = gamma + (size_t)r * 8;   // uniform
            const float* __restrict__ e  = eta   + (size_t)r * 8;   // uniform
            const float* __restrict__ zc = zeta  + (size_t)r * 8;   // uniform
            const float ghr = sigmoidf_(G[r]);
            float Ar = ghr;
            #pragma unroll
            for (int i = 0; i < 5; ++i) Ar = Ar * Ar;   // gh^32
            const int k0 = t0 / L_CHUNK;
            float th = 0.0f;
            for (int jj = 0; jj < k0; ++jj)
                th = fmaf(Ar, th, U[(size_t)jj * R_RUNS + r]);
            float bprev = 0.0f;
            if (t0 > 0) {
                const float* __restrict__ zr = Zt + (size_t)(t0 - 1) * 8;
                bprev = zr[0]*gc[0] + zr[1]*gc[1] + zr[2]*gc[2] + zr[3]*gc[3]
                      + zr[4]*gc[4] + zr[5]*gc[5] + zr[6]*gc[6] + zr[7]*gc[7];
            }
            float myval = 0.0f;
            for (int j2 = 0; j2 < TBW; ++j2) {
                th = fmaf(ghr, th, bprev);
                const float* __restrict__ zr = Zt + (size_t)(t0 + j2) * 8;
                bprev = zr[0]*gc[0] + zr[1]*gc[1] + zr[2]*gc[2] + zr[3]*gc[3]
                      + zr[4]*gc[4] + zr[5]*gc[5] + zr[6]*gc[6] + zr[7]*gc[7];
                myval = (lane == j2) ? th : myval;
            }
            float s = myval;
            s = fmaf(xa.x, e[0], s);  s = fmaf(xa.y, e[1], s);
            s = fmaf(xa.z, e[2], s);  s = fmaf(xa.w, e[3], s);
            s = fmaf(xb.x, e[4], s);  s = fmaf(xb.y, e[5], s);
            s = fmaf(xb.z, e[6], s);  s = fmaf(xb.w, e[7], s);
            s = fmaf(za.x, zc[0], s); s = fmaf(za.y, zc[1], s);
            s = fmaf(za.z, zc[2], s); s = fmaf(za.w, zc[3], s);
            s = fmaf(zb.x, zc[4], s); s = fmaf(zb.y, zc[5], s);
            s = fmaf(zb.z, zc[6], s); s = fmaf(zb.w, zc[7], s);
            out[(size_t)r * T_STEPS + t] = s;
        }
    }
}

// ---------------------------------------------------------------------------
extern "C" void kernel_launch(void* const* d_in, const int* in_sizes, int n_in,
                              void* d_out, int out_size, void* d_ws, size_t ws_size,
                              hipStream_t stream)
{
    const float* Xt    = (const float*)d_in[0];
    const float* Zt    = (const float*)d_in[1];
    const float* G     = (const float*)d_in[2];
    const float* eta   = (const float*)d_in[3];
    const float* zeta  = (const float*)d_in[4];
    const float* gamma = (const float*)d_in[5];
    float* out = (float*)d_out;

    // ws: U[64][4096] (1 MB) | W[2048][8] (64 KB)
    float* U = (float*)d_ws;
    float* W = U + (size_t)K_CHUNKS * R_RUNS;

    const dim3 blk(256);
    const dim3 grid(1024);   // K1: 4096 (k,g) waves; KB: 4096 (tb,rg) waves

    dlm_k1<<<grid, blk, 0, stream>>>(Zt, G, gamma, U, W);
    dlm_kb<<<grid, blk, 0, stream>>>(Xt, Zt, G, eta, zeta, gamma, U, W, out);
}